// Round 9
// baseline (245.631 us; speedup 1.0000x reference)
//
#include <hip/hip_runtime.h>
#include <stdint.h>

typedef __attribute__((ext_vector_type(8))) __bf16 bf16x8;
typedef __attribute__((ext_vector_type(4))) float f32x4;

// Selected upper-tri circular-adjacency pairs (r,c), row-major triu order. K=64.
__device__ const unsigned char dR[64] = {
  0,0,0,0,0,0,0,
  1,1,1,1,1,1,
  2,2,2,2,2,
  3,3,3,3,
  4,4,4,4,
  5,5,5,5,
  6,6,6,6,
  7,7,7,7,
  8,8,8,8,
  9,9,9,9,
  10,10,10,10,
  11,11,11,11,
  12,12,12,12,
  13,13,13,
  14,14,
  15};
__device__ const unsigned char dC[64] = {
  0,1,2,3,13,14,15,
  1,2,3,4,14,15,
  2,3,4,5,15,
  3,4,5,6,
  4,5,6,7,
  5,6,7,8,
  6,7,8,9,
  7,8,9,10,
  8,9,10,11,
  9,10,11,12,
  10,11,12,13,
  11,12,13,14,
  12,13,14,15,
  13,14,15,
  14,15,
  15};

__device__ __forceinline__ unsigned short f2bf(float x){
  unsigned u = __builtin_bit_cast(unsigned, x);
  return (unsigned short)((u + 0x7FFFu + ((u >> 16) & 1u)) >> 16);
}

// fp32 -> bf16 weight conversion + K-STEP PACKING into workspace.
// W1 packed as [64 ks][512 col][32 k], W2 as [16 ks][512 col][32 k] (bf16):
// a wave's 8 fragment loads for one k-step are then 8 x 1KB contiguous.
__global__ void conv_w_kernel(const float* __restrict__ w1, const float* __restrict__ w2,
                              unsigned short* __restrict__ o1, unsigned short* __restrict__ o2){
  int i = blockIdx.x * 256 + threadIdx.x;
  if (i < 262144){                                  // W1: [512][2048] fp32, float4 idx
    float4 v = ((const float4*)w1)[i];
    ushort4 pk; pk.x=f2bf(v.x); pk.y=f2bf(v.y); pk.z=f2bf(v.z); pk.w=f2bf(v.w);
    const int col = i >> 9;
    const int kb  = (i & 511) << 2;                 // k base (multiple of 4)
    const int ks  = kb >> 5, ko = kb & 31;
    ((ushort4*)o1)[(ks << 12) + (col << 3) + (ko >> 2)] = pk;
  } else {
    int j = i - 262144;
    if (j < 65536){                                 // W2: [512][512] fp32
      float4 v = ((const float4*)w2)[j];
      ushort4 pk; pk.x=f2bf(v.x); pk.y=f2bf(v.y); pk.z=f2bf(v.z); pk.w=f2bf(v.w);
      const int col = j >> 7;
      const int kb  = (j & 127) << 2;
      const int ks  = kb >> 5, ko = kb & 31;
      ((ushort4*)o2)[(ks << 12) + (col << 3) + (ko >> 2)] = pk;
    }
  }
}

// LDS (48 KiB/block -> 2 blocks/CU):
//   phase 1: gather A-tile dbuf 2 x 3072 B @ 0 / 3072  ([kb4][48 row][16B])
//   phase 2: A1 [48 row][512 h] bf16 XOR-swizzled @ [0, 49152) (aliases, post-barrier)
#define LB0 0
#define LB1 3072

// issue 6 gather register loads into static slot S (slot parity PAR fixed)
#define GISS(S, PAR, FV) do{ const float* xf_ = xb + ((long)(FV) << 16);                  \
  _Pragma("unroll") for (int o_ = 0; o_ < 3; ++o_)                                        \
  _Pragma("unroll") for (int e_ = 0; e_ < 2; ++e_)                                        \
    g##S[o_][e_] = xf_[poff[PAR][o_][e_]]; }while(0)

// W1 fragment loads, direct from L2 (packed layout: 1KB contiguous per instr)
#define WLOAD(DST, N) do{ _Pragma("unroll") for (int cn_ = 0; cn_ < 8; ++cn_)             \
  DST[cn_] = *(const bf16x8*)(w1c + (((long)(N)) << 15) + wfo[cn_]); }while(0)

// cvt slot -> ds_write A-tile into buffer BUF
#define CVTWR(S, BUF) do{ _Pragma("unroll") for (int o_ = 0; o_ < 3; ++o_){               \
  unsigned pv_ = (unsigned)f2bf(g##S[o_][0]) | ((unsigned)f2bf(g##S[o_][1]) << 16);       \
  *(unsigned*)(lds + (BUF) + awr + (o_ << 8)) = pv_; } }while(0)

// 3 A-frag ds_read_b128 + 24 MFMA (W frags in registers)
#define MM(ABUF, BW) do{ bf16x8 af_[3];                                                   \
  _Pragma("unroll") for (int fm_ = 0; fm_ < 3; ++fm_)                                     \
    af_[fm_] = *(const bf16x8*)(lds + (ABUF) + ard + fm_*256);                            \
  _Pragma("unroll") for (int cn_ = 0; cn_ < 8; ++cn_)                                     \
  _Pragma("unroll") for (int fm_ = 0; fm_ < 3; ++fm_)                                     \
    acc[fm_][cn_] = __builtin_amdgcn_mfma_f32_16x16x32_bf16(af_[fm_], BW[cn_], acc[fm_][cn_], 0, 0, 0); \
}while(0)

// LDS-only barrier (all global loads are register loads -> compiler-counted vmcnt)
#define BAR() do{ asm volatile("s_waitcnt lgkmcnt(0)" ::: "memory");                      \
  __builtin_amdgcn_s_barrier(); asm volatile("" ::: "memory"); }while(0)

// phase-2 sub-step: 3 swizzled A1 reads + 24 MFMA (W2 frags in cc[])
#define A2SUB(ss, cc) do{ bf16x8 a2_[3];                                                  \
  _Pragma("unroll") for (int fm_ = 0; fm_ < 3; ++fm_){                                    \
    int byt_ = ((fm_ * 16 + lr) << 10) + ((ss) << 6) + (q << 4);                          \
    byt_ ^= (lr & 7) << 4;                                                                \
    a2_[fm_] = *(const bf16x8*)(lds + byt_); }                                            \
  _Pragma("unroll") for (int cn_ = 0; cn_ < 8; ++cn_)                                     \
  _Pragma("unroll") for (int fm_ = 0; fm_ < 3; ++fm_)                                     \
    acc2[fm_][cn_] = __builtin_amdgcn_mfma_f32_16x16x32_bf16(a2_[fm_], cc[cn_], acc2[fm_][cn_], 0, 0, 0); \
}while(0)

// Block = (b, 16-t tile): 512 blocks x 256 threads (4 waves) -> 2 blocks/CU.
// Wave tile [48m x 128n]; W direct L2->reg; gather dbuf in LDS only.
__global__ __launch_bounds__(256, 2)
void fused_kernel(const float* __restrict__ x,
                  const float* __restrict__ b1v,
                  const float* __restrict__ b2v,
                  const unsigned short* __restrict__ w1b,
                  const unsigned short* __restrict__ w2b,
                  float* __restrict__ out)
{
  __shared__ char lds[49152];
  const int bid = blockIdx.x;
  const int wg  = ((bid & 7) << 6) | (bid >> 3);   // bijective XCD swizzle (512 % 8 == 0)
  const int b   = wg >> 4;
  const int t0  = (wg & 15) << 4;

  const int tid  = threadIdx.x;
  const int w    = tid >> 6;          // wave 0..3
  const int lane = tid & 63;
  const int q    = lane >> 4;
  const int lr   = lane & 15;
  const int u    = tid >> 4;          // 0..15: k-pair index for gather
  const int tt   = tid & 15;          // t within tile for gather

  // gather source offsets: k = par*32 + 2u + e
  int poff[2][3][2];
#pragma unroll
  for (int par = 0; par < 2; ++par)
#pragma unroll
    for (int e = 0; e < 2; ++e){
      const int k = par * 32 + 2 * u + e;
      const int r = dR[k], c = dC[k];
#pragma unroll
      for (int o = 0; o < 3; ++o){
        const int v = o - 1;                         // mean over o is order-free
        poff[par][o][e] = ((((r - v) & 15) << 4) | ((c - v) & 15)) << 8;
      }
    }
  const float* xb = x + (((long)b << 21) + t0 + tt);

  // A-tile write: [kb4][row48][16B], kb stride 768; row = o*16+tt (o stride 256B)
  const int awr = ((u >> 2) * 768) + (tt << 4) + ((u & 3) << 2);    // + o<<8
  // A-frag read: row = fm*16+lr, k = 8q+e
  const int ard = q * 768 + (lr << 4);                              // + fm*256
  // W fragment offsets into packed [ks][512 col][32 k] layout
  const char* w1c = (const char*)w1b;
  const char* w2c = (const char*)w2b;
  int wfo[8];
  float b1c[8], b2c[8];
#pragma unroll
  for (int cn = 0; cn < 8; ++cn){
    const int col = (w << 7) + (cn << 4) + lr;
    wfo[cn] = (col << 6) + (q << 4);
    b1c[cn] = b1v[col];
    b2c[cn] = b2v[col];
  }

  f32x4 acc[3][8];
#pragma unroll
  for (int fm = 0; fm < 3; ++fm)
#pragma unroll
    for (int cn = 0; cn < 8; ++cn)
      acc[fm][cn] = f32x4{0.f, 0.f, 0.f, 0.f};

  float g0[3][2], g1[3][2], g2[3][2], g3[3][2];
  bf16x8 bwA[8], bwB[8];

  // ---------------- prologue ----------------
  // tile0 -> LB0 (direct); g1 <- tile1, g2 <- tile2 in flight; bwA <- W step 0
  {
    float gp[3][2];
#pragma unroll
    for (int o_ = 0; o_ < 3; ++o_)
#pragma unroll
      for (int e_ = 0; e_ < 2; ++e_)
        gp[o_][e_] = xb[poff[0][o_][e_]];
    GISS(1, 1, 0);                   // tile 1: f=0, par=1
    GISS(2, 0, 1);                   // tile 2: f=1, par=0
    WLOAD(bwA, 0);
#pragma unroll
    for (int o_ = 0; o_ < 3; ++o_){
      unsigned pv_ = (unsigned)f2bf(gp[o_][0]) | ((unsigned)f2bf(gp[o_][1]) << 16);
      *(unsigned*)(lds + LB0 + awr + (o_ << 8)) = pv_;
    }
  }
  BAR();

  // ---------------- phase 1: 64 K-steps (4x unrolled), LDS-only barriers --------
  // step N: issue gather tile N+3, load W frags N+1 (regs), compute tile N,
  //         cvt+write tile N+1, barrier.
#pragma unroll 1
  for (int it = 0; it < 16; ++it){
    const bool lastit = (it == 15);
    // j=0 (N=4it)
    GISS(3, 1, (it << 1) + 1);
    WLOAD(bwB, (it << 2) + 1);
    MM(LB0, bwA);
    CVTWR(1, LB1);
    BAR();
    // j=1 (N=4it+1)
    if (!lastit) GISS(0, 0, (it << 1) + 2);
    WLOAD(bwA, (it << 2) + 2);
    MM(LB1, bwB);
    CVTWR(2, LB0);
    BAR();
    // j=2 (N=4it+2)
    if (!lastit) GISS(1, 1, (it << 1) + 2);
    WLOAD(bwB, (it << 2) + 3);
    MM(LB0, bwA);
    CVTWR(3, LB1);
    BAR();
    // j=3 (N=4it+3)
    if (!lastit){
      GISS(2, 0, (it << 1) + 3);
      WLOAD(bwA, (it << 2) + 4);
    }
    MM(LB1, bwB);
    if (!lastit) CVTWR(0, LB0);
    BAR();
  }

  // ---------------- epilogue 1: bias + leaky -> A1 bf16 (XOR-swizzled) --------
#pragma unroll
  for (int cn = 0; cn < 8; ++cn){
    const int h = (w << 7) + (cn << 4) + lr;
#pragma unroll
    for (int fm = 0; fm < 3; ++fm)
#pragma unroll
      for (int r = 0; r < 4; ++r){
        float vv = acc[fm][cn][r] + b1c[cn];
        vv = vv > 0.f ? vv : 0.01f * vv;
        const int row = (fm << 4) + (q << 2) + r;    // D row = 4*(lane>>4)+reg
        int byt = (row << 10) + (h << 1);
        byt ^= (row & 7) << 4;
        *(unsigned short*)(lds + byt) = f2bf(vv);
      }
  }
  BAR();

  // ---------------- phase 2: K=512 vs packed W2 (direct L2 regs), barrier-free --
  f32x4 acc2[3][8];
#pragma unroll
  for (int fm = 0; fm < 3; ++fm)
#pragma unroll
    for (int cn = 0; cn < 8; ++cn)
      acc2[fm][cn] = f32x4{0.f, 0.f, 0.f, 0.f};

  bf16x8 c0[8], c1[8];
#pragma unroll
  for (int cn = 0; cn < 8; ++cn) c0[cn] = *(const bf16x8*)(w2c + wfo[cn]);

#pragma unroll 1
  for (int it2 = 0; it2 < 8; ++it2){
    const int s0 = it2 << 1;
#pragma unroll
    for (int cn = 0; cn < 8; ++cn)
      c1[cn] = *(const bf16x8*)(w2c + (((long)(s0 + 1)) << 15) + wfo[cn]);
    A2SUB(s0, c0);
    if (it2 < 7){
#pragma unroll
      for (int cn = 0; cn < 8; ++cn)
        c0[cn] = *(const bf16x8*)(w2c + (((long)(s0 + 2)) << 15) + wfo[cn]);
    }
    A2SUB(s0 + 1, c1);
  }

  // ---------------- epilogue 2: bias + leaky + mean(o=fm) -> [B,H,T] ------------
#pragma unroll
  for (int cn = 0; cn < 8; ++cn){
    const int h = (w << 7) + (cn << 4) + lr;
    f32x4 ov;
#pragma unroll
    for (int r = 0; r < 4; ++r){
      float s = 0.f;
#pragma unroll
      for (int fm = 0; fm < 3; ++fm){
        float vv = acc2[fm][cn][r] + b2c[cn];
        vv = vv > 0.f ? vv : 0.01f * vv;
        s += vv;
      }
      ov[r] = s * (1.f / 3.f);
    }
    *(f32x4*)(out + (((long)b * 512 + h) << 8) + t0 + (q << 2)) = ov;
  }
}

extern "C" void kernel_launch(void* const* d_in, const int* in_sizes, int n_in,
                              void* d_out, int out_size, void* d_ws, size_t ws_size,
                              hipStream_t stream){
  const float* x  = (const float*)d_in[0];
  const float* w1 = (const float*)d_in[1];
  const float* b1 = (const float*)d_in[2];
  const float* w2 = (const float*)d_in[3];
  const float* b2 = (const float*)d_in[4];
  unsigned short* w1b = (unsigned short*)d_ws;            // packed W1: 2 MiB
  unsigned short* w2b = w1b + 512 * 2048;                 // packed W2: 0.5 MiB
  conv_w_kernel<<<1280, 256, 0, stream>>>(w1, w2, w1b, w2b);
  fused_kernel<<<512, 256, 0, stream>>>(x, b1, b2, w1b, w2b, (float*)d_out);
}

// Round 10
// 127.279 us; speedup vs baseline: 1.9299x; 1.9299x over previous
//
#include <hip/hip_runtime.h>
#include <stdint.h>

typedef __attribute__((ext_vector_type(8))) __bf16 bf16x8;
typedef __attribute__((ext_vector_type(4))) float f32x4;

// Selected upper-tri circular-adjacency pairs (r,c), row-major triu order. K=64.
__device__ const unsigned char dR[64] = {
  0,0,0,0,0,0,0,
  1,1,1,1,1,1,
  2,2,2,2,2,
  3,3,3,3,
  4,4,4,4,
  5,5,5,5,
  6,6,6,6,
  7,7,7,7,
  8,8,8,8,
  9,9,9,9,
  10,10,10,10,
  11,11,11,11,
  12,12,12,12,
  13,13,13,
  14,14,
  15};
__device__ const unsigned char dC[64] = {
  0,1,2,3,13,14,15,
  1,2,3,4,14,15,
  2,3,4,5,15,
  3,4,5,6,
  4,5,6,7,
  5,6,7,8,
  6,7,8,9,
  7,8,9,10,
  8,9,10,11,
  9,10,11,12,
  10,11,12,13,
  11,12,13,14,
  12,13,14,15,
  13,14,15,
  14,15,
  15};

__device__ __forceinline__ unsigned short f2bf(float x){
  unsigned u = __builtin_bit_cast(unsigned, x);
  return (unsigned short)((u + 0x7FFFu + ((u >> 16) & 1u)) >> 16);
}

__device__ __forceinline__ void gl16(const void* g, void* l){
  __builtin_amdgcn_global_load_lds((const __attribute__((address_space(1))) unsigned int*)g,
                                   (__attribute__((address_space(3))) unsigned int*)l,
                                   16, 0, 0);
}

// fp32 -> bf16 conversion + K-STEP PACKING: W1 -> [64 ks][512 col][32 k] bf16,
// W2 -> [16 ks][512 col][32 k] bf16. Contiguous 1KB per (ks, 16-col chunk).
__global__ void conv_w_kernel(const float* __restrict__ w1, const float* __restrict__ w2,
                              unsigned short* __restrict__ o1, unsigned short* __restrict__ o2){
  int i = blockIdx.x * 256 + threadIdx.x;
  if (i < 262144){                                  // W1: [512][2048] fp32, float4 idx
    float4 v = ((const float4*)w1)[i];
    ushort4 pk; pk.x=f2bf(v.x); pk.y=f2bf(v.y); pk.z=f2bf(v.z); pk.w=f2bf(v.w);
    const int col = i >> 9;
    const int kb  = (i & 511) << 2;
    const int ks  = kb >> 5, ko = kb & 31;
    ((ushort4*)o1)[(ks << 12) + (col << 3) + (ko >> 2)] = pk;
  } else {
    int j = i - 262144;
    if (j < 65536){                                 // W2: [512][512] fp32
      float4 v = ((const float4*)w2)[j];
      ushort4 pk; pk.x=f2bf(v.x); pk.y=f2bf(v.y); pk.z=f2bf(v.z); pk.w=f2bf(v.w);
      const int col = j >> 7;
      const int kb  = (j & 127) << 2;
      const int ks  = kb >> 5, ko = kb & 31;
      ((ushort4*)o2)[(ks << 12) + (col << 3) + (ko >> 2)] = pk;
    }
  }
}

// LDS: phase 1: W dbuf 2x32KB @ 0/32768 ([512 col][4 slot][16B], slot-swizzled),
//               gather A dbuf 2x6144 @ 65536/71680 ([kb4][96 row][16B]).
//      phase 2: A1 [96 row][512 h] bf16 XOR-swizzled @ [0, 98304) (aliases, post-barrier)
#define LW0 0
#define LW1 32768
#define LA0 65536
#define LA1 71680

// stage W k-step KS into buffer WBUF (wave-private 64 cols, 4 x gl16, packed source)
#define WSTAGE(WBUF, KS) do{ _Pragma("unroll") for (int i_ = 0; i_ < 4; ++i_)             \
  gl16((const char*)w1b + (((long)(KS)) << 15) + wso[i_], lds + (WBUF) + wdb[i_]); }while(0)

// counted vmcnt: N = loads issued after the gl16 batch we need (in-order completion)
#define VW(N) asm volatile("s_waitcnt vmcnt(" #N ")" ::: "memory")

// issue 6 gather register loads into static slot S (parity PAR fixed per slot)
#define GISS(S, PAR, FV) do{ const float* xf_ = xb + ((long)(FV) << 16);                  \
  _Pragma("unroll") for (int o_ = 0; o_ < 3; ++o_)                                        \
  _Pragma("unroll") for (int e_ = 0; e_ < 2; ++e_)                                        \
    g##S[o_][e_] = xf_[poff[PAR][o_][e_]]; }while(0)

// cvt slot -> ds_write A-tile into buffer BUF (compiler inserts exact vmcnt for g regs)
#define CVTWR(S, BUF) do{ _Pragma("unroll") for (int o_ = 0; o_ < 3; ++o_){               \
  unsigned pv_ = (unsigned)f2bf(g##S[o_][0]) | ((unsigned)f2bf(g##S[o_][1]) << 16);       \
  *(unsigned*)(lds + (BUF) + awr + (o_ << 9)) = pv_; } }while(0)

// 6 A-frag + 4 W-frag ds_read_b128, 24 MFMA
#define MM(ABUF, WBUF) do{ bf16x8 af_[6], bw_[4];                                         \
  _Pragma("unroll") for (int fm_ = 0; fm_ < 6; ++fm_)                                     \
    af_[fm_] = *(const bf16x8*)(lds + (ABUF) + ard + fm_*256);                            \
  _Pragma("unroll") for (int cn_ = 0; cn_ < 4; ++cn_)                                     \
    bw_[cn_] = *(const bf16x8*)(lds + (WBUF) + wrd[cn_]);                                 \
  _Pragma("unroll") for (int cn_ = 0; cn_ < 4; ++cn_)                                     \
  _Pragma("unroll") for (int fm_ = 0; fm_ < 6; ++fm_)                                     \
    acc[fm_][cn_] = __builtin_amdgcn_mfma_f32_16x16x32_bf16(af_[fm_], bw_[cn_], acc[fm_][cn_], 0, 0, 0); \
}while(0)

// LDS-only barrier: NO vmcnt drain (gl16 correctness handled by counted VW)
#define BAR() do{ asm volatile("s_waitcnt lgkmcnt(0)" ::: "memory");                      \
  __builtin_amdgcn_s_barrier(); asm volatile("" ::: "memory"); }while(0)

// one steady K-step: stage next W, counted wait, issue gather (2-step flight),
// compute current, write next A tile, barrier.
#define STEPJ(ABUF, WRD_, WWR_, KS, GS, GP, GF, CS, CBUF) do{                             \
  WSTAGE(WWR_, KS); VW(14); GISS(GS, GP, GF);                                             \
  MM(ABUF, WRD_); CVTWR(CS, CBUF); BAR(); }while(0)

#define A2SUB(ss, cc) do{                                                                 \
  bf16x8 a2[6];                                                                           \
  _Pragma("unroll") for (int fm = 0; fm < 6; ++fm){                                       \
    int byt = (((fm << 4) + lr) << 10) + ((ss) << 6) + (q << 4);                          \
    byt ^= (lr & 7) << 4;                                                                 \
    a2[fm] = *(const bf16x8*)(lds + byt);                                                 \
  }                                                                                       \
  _Pragma("unroll") for (int cn = 0; cn < 4; ++cn)                                        \
    _Pragma("unroll") for (int fm = 0; fm < 6; ++fm)                                      \
      acc2[fm][cn] = __builtin_amdgcn_mfma_f32_16x16x32_bf16(a2[fm], cc[cn], acc2[fm][cn], 0, 0, 0); \
}while(0)

// Block = (b, 32-t tile): 256 blocks, 512 threads (8 waves). Each wave: [96m x 64n].
__global__ __launch_bounds__(512, 2)
void fused_kernel(const float* __restrict__ x,
                  const float* __restrict__ b1v,
                  const float* __restrict__ b2v,
                  const unsigned short* __restrict__ w1b,
                  const unsigned short* __restrict__ w2b,
                  float* __restrict__ out)
{
  __shared__ char lds[98304];
  const int bid = blockIdx.x;
  const int b   = bid >> 3;
  const int t0  = (bid & 7) << 5;

  const int tid  = threadIdx.x;
  const int w    = tid >> 6;
  const int lane = tid & 63;
  const int q    = lane >> 4;
  const int lr   = lane & 15;
  const int u    = tid >> 5;          // [0,16): k-pair index for gather
  const int tt   = tid & 31;          // t within tile for gather

  // gather source offsets: k = par*32 + 2u + e
  int poff[2][3][2];
#pragma unroll
  for (int par = 0; par < 2; ++par)
#pragma unroll
    for (int e = 0; e < 2; ++e){
      const int k = par * 32 + 2 * u + e;
      const int r = dR[k], c = dC[k];
#pragma unroll
      for (int o = 0; o < 3; ++o){
        const int v = o - 1;                         // mean over o is order-free
        poff[par][o][e] = ((((r - v) & 15) << 4) | ((c - v) & 15)) << 8;
      }
    }
  const float* xb = x + (((long)b << 21) + t0 + tt);

  // A-tile: [kb4][row96][16B], kb stride 1536
  const int awr = ((u >> 2) * 1536) + (tt << 4) + ((u & 3) << 2);   // + o*512
  const int ard = q * 1536 + (lr << 4);                              // + fm*256
  // W-frag read: [col][4 slot][16B], slot = q ^ ((col>>1)&3)
  int wrd[4];
#pragma unroll
  for (int cn = 0; cn < 4; ++cn){
    const int col = (w << 6) + (cn << 4) + lr;
    wrd[cn] = col * 64 + ((q ^ ((col >> 1) & 3)) << 4);
  }
  // W stage: linear LDS dest (wave-uniform), inverse-swizzled packed global source
  int wso[4], wdb[4];
#pragma unroll
  for (int i = 0; i < 4; ++i){
    const int colb = (w << 6) + (i << 4);
    const int col  = colb + (lane >> 2);
    wso[i] = col * 64 + (((lane & 3) ^ ((col >> 1) & 3)) << 4);
    wdb[i] = colb * 64;
  }
  float b1c[4];
#pragma unroll
  for (int cn = 0; cn < 4; ++cn) b1c[cn] = b1v[(w << 6) + (cn << 4) + lr];

  f32x4 acc[6][4];
#pragma unroll
  for (int fm = 0; fm < 6; ++fm)
#pragma unroll
    for (int cn = 0; cn < 4; ++cn)
      acc[fm][cn] = f32x4{0.f, 0.f, 0.f, 0.f};

  float g0[3][2], g1[3][2], g2[3][2], g3[3][2];

  // ---------------- prologue ----------------
  // order: [gp 6][WSTAGE 8][G1 6][G2 6]; cvt gp (auto-wait, oldest); VW(12) ensures
  // WSTAGE done while leaving G1,G2 in flight; barrier.
  {
    float gp[3][2];
#pragma unroll
    for (int o_ = 0; o_ < 3; ++o_)
#pragma unroll
      for (int e_ = 0; e_ < 2; ++e_)
        gp[o_][e_] = xb[poff[0][o_][e_]];          // tile 0 (f=0, par=0)
    WSTAGE(LW0, 0);                                // W k-step 0
    GISS(1, 1, 0);                                 // tile 1 (f=0, par=1)
    GISS(2, 0, 1);                                 // tile 2 (f=1, par=0)
#pragma unroll
    for (int o_ = 0; o_ < 3; ++o_){
      unsigned pv_ = (unsigned)f2bf(gp[o_][0]) | ((unsigned)f2bf(gp[o_][1]) << 16);
      *(unsigned*)(lds + LA0 + awr + (o_ << 9)) = pv_;
    }
    VW(12);
    BAR();
  }

  // ---------------- phase 1: 64 K-steps, counted vmcnt, LDS-only barriers --------
#pragma unroll 1
  for (int it = 0; it < 15; ++it){
    STEPJ(LA0, LW0, LW1, (it << 2) + 1, 3, 1, (it << 1) + 1, 1, LA1);
    STEPJ(LA1, LW1, LW0, (it << 2) + 2, 0, 0, (it << 1) + 2, 2, LA0);
    STEPJ(LA0, LW0, LW1, (it << 2) + 3, 1, 1, (it << 1) + 2, 3, LA1);
    STEPJ(LA1, LW1, LW0, (it << 2) + 4, 2, 0, (it << 1) + 3, 0, LA0);
  }
  // tail (it = 15): steps 60..63, no gathers beyond tile 63, drain gracefully
  STEPJ(LA0, LW0, LW1, 61, 3, 1, 31, 1, LA1);      // step 60; g3 <- tile 63
  WSTAGE(LW0, 62); VW(14); MM(LA1, LW1); CVTWR(2, LA0); BAR();   // step 61
  WSTAGE(LW1, 63); VW(8);  MM(LA0, LW0); CVTWR(3, LA1); BAR();   // step 62
  VW(0);           MM(LA1, LW1);                         BAR();  // step 63

  // ---------------- epilogue 1: bias + leaky -> A1 bf16 (XOR-swizzled) --------
#pragma unroll
  for (int cn = 0; cn < 4; ++cn){
    const int h  = (w << 6) + (cn << 4) + lr;
#pragma unroll
    for (int fm = 0; fm < 6; ++fm)
#pragma unroll
      for (int r = 0; r < 4; ++r){
        float vv = acc[fm][cn][r] + b1c[cn];
        vv = vv > 0.f ? vv : 0.01f * vv;
        const int row = (fm << 4) + (q << 2) + r;    // D row = 4*(lane>>4)+reg
        int byt = (row << 10) + (h << 1);
        byt ^= (row & 7) << 4;
        *(unsigned short*)(lds + byt) = f2bf(vv);
      }
  }
  BAR();

  // ---------------- phase 2: K=512 vs packed W2 (L2 reg frags), barrier-free ----
  int w2off[4];
  float b2c[4];
#pragma unroll
  for (int cn = 0; cn < 4; ++cn){
    const int col = (w << 6) + (cn << 4) + lr;
    w2off[cn] = col * 64 + (q << 4);
    b2c[cn] = b2v[col];
  }
  const char* w2c = (const char*)w2b;
  f32x4 acc2[6][4];
#pragma unroll
  for (int fm = 0; fm < 6; ++fm)
#pragma unroll
    for (int cn = 0; cn < 4; ++cn)
      acc2[fm][cn] = f32x4{0.f, 0.f, 0.f, 0.f};

  bf16x8 c0[4], c1[4];
#pragma unroll
  for (int cn = 0; cn < 4; ++cn) c0[cn] = *(const bf16x8*)(w2c + w2off[cn]);

#pragma unroll 1
  for (int it2 = 0; it2 < 8; ++it2){
    const int s0 = it2 << 1;
#pragma unroll
    for (int cn = 0; cn < 4; ++cn)
      c1[cn] = *(const bf16x8*)(w2c + (((long)(s0 + 1)) << 15) + w2off[cn]);
    A2SUB(s0, c0);
    if (it2 < 7){
#pragma unroll
      for (int cn = 0; cn < 4; ++cn)
        c0[cn] = *(const bf16x8*)(w2c + (((long)(s0 + 2)) << 15) + w2off[cn]);
    }
    A2SUB(s0 + 1, c1);
  }

  // ---------------- epilogue 2: bias + leaky + mean(o) -> [B,H,T] -------------
#pragma unroll
  for (int cn = 0; cn < 4; ++cn){
    const int h  = (w << 6) + (cn << 4) + lr;
#pragma unroll
    for (int p = 0; p < 2; ++p){
      f32x4 ov;
#pragma unroll
      for (int r = 0; r < 4; ++r){
        float s = 0.f;
#pragma unroll
        for (int oo = 0; oo < 3; ++oo){
          float vv = acc2[oo * 2 + p][cn][r] + b2c[cn];
          vv = vv > 0.f ? vv : 0.01f * vv;
          s += vv;
        }
        ov[r] = s * (1.f / 3.f);
      }
      *(f32x4*)(out + (((long)b * 512 + h) << 8) + t0 + (p << 4) + (q << 2)) = ov;
    }
  }
}

extern "C" void kernel_launch(void* const* d_in, const int* in_sizes, int n_in,
                              void* d_out, int out_size, void* d_ws, size_t ws_size,
                              hipStream_t stream){
  const float* x  = (const float*)d_in[0];
  const float* w1 = (const float*)d_in[1];
  const float* b1 = (const float*)d_in[2];
  const float* w2 = (const float*)d_in[3];
  const float* b2 = (const float*)d_in[4];
  unsigned short* w1b = (unsigned short*)d_ws;            // packed W1: 2 MiB
  unsigned short* w2b = w1b + 512 * 2048;                 // packed W2: 0.5 MiB
  conv_w_kernel<<<1280, 256, 0, stream>>>(w1, w2, w1b, w2b);
  fused_kernel<<<256, 512, 0, stream>>>(x, b1, b2, w1b, w2b, (float*)d_out);
}

// Round 11
// 98.936 us; speedup vs baseline: 2.4827x; 1.2865x over previous
//
#include <hip/hip_runtime.h>
#include <stdint.h>

typedef __attribute__((ext_vector_type(8))) __bf16 bf16x8;
typedef __attribute__((ext_vector_type(4))) float f32x4;

// Selected upper-tri circular-adjacency pairs (r,c), row-major triu order. K=64.
__device__ const unsigned char dR[64] = {
  0,0,0,0,0,0,0,
  1,1,1,1,1,1,
  2,2,2,2,2,
  3,3,3,3,
  4,4,4,4,
  5,5,5,5,
  6,6,6,6,
  7,7,7,7,
  8,8,8,8,
  9,9,9,9,
  10,10,10,10,
  11,11,11,11,
  12,12,12,12,
  13,13,13,
  14,14,
  15};
__device__ const unsigned char dC[64] = {
  0,1,2,3,13,14,15,
  1,2,3,4,14,15,
  2,3,4,5,15,
  3,4,5,6,
  4,5,6,7,
  5,6,7,8,
  6,7,8,9,
  7,8,9,10,
  8,9,10,11,
  9,10,11,12,
  10,11,12,13,
  11,12,13,14,
  12,13,14,15,
  13,14,15,
  14,15,
  15};

__device__ __forceinline__ unsigned short f2bf(float x){
  unsigned u = __builtin_bit_cast(unsigned, x);
  return (unsigned short)((u + 0x7FFFu + ((u >> 16) & 1u)) >> 16);
}

__device__ __forceinline__ void gl16(const void* g, void* l){
  __builtin_amdgcn_global_load_lds((const __attribute__((address_space(1))) unsigned int*)g,
                                   (__attribute__((address_space(3))) unsigned int*)l,
                                   16, 0, 0);
}

// fp32 -> bf16 conversion + K-STEP PACKING: W1 -> [64 ks][512 col][32 k] bf16,
// W2 -> [16 ks][512 col][32 k] bf16. Contiguous 1KB per (ks, 16-col chunk).
__global__ void conv_w_kernel(const float* __restrict__ w1, const float* __restrict__ w2,
                              unsigned short* __restrict__ o1, unsigned short* __restrict__ o2){
  int i = blockIdx.x * 256 + threadIdx.x;
  if (i < 262144){                                  // W1: [512][2048] fp32, float4 idx
    float4 v = ((const float4*)w1)[i];
    ushort4 pk; pk.x=f2bf(v.x); pk.y=f2bf(v.y); pk.z=f2bf(v.z); pk.w=f2bf(v.w);
    const int col = i >> 9;
    const int kb  = (i & 511) << 2;
    const int ks  = kb >> 5, ko = kb & 31;
    ((ushort4*)o1)[(ks << 12) + (col << 3) + (ko >> 2)] = pk;
  } else {
    int j = i - 262144;
    if (j < 65536){                                 // W2: [512][512] fp32
      float4 v = ((const float4*)w2)[j];
      ushort4 pk; pk.x=f2bf(v.x); pk.y=f2bf(v.y); pk.z=f2bf(v.z); pk.w=f2bf(v.w);
      const int col = j >> 7;
      const int kb  = (j & 127) << 2;
      const int ks  = kb >> 5, ko = kb & 31;
      ((ushort4*)o2)[(ks << 12) + (col << 3) + (ko >> 2)] = pk;
    }
  }
}

// LDS (152 KiB): W 4-buf @ 0/32768/65536/98304 ([512 col][4 slot][16B], slot-swizzled),
//                gather A 4-buf @ 131072 + i*6144 ([kb4][96 row][16B]).
// phase 2: A1 [96 row][512 h] bf16 XOR-swizzled @ [0, 98304) (aliases W bufs, post-barrier)
#define LW0 0
#define LW1 32768
#define LW2 65536
#define LW3 98304
#define LA_0 131072
#define LA_1 137216
#define LA_2 143360
#define LA_3 149504

// stage W k-step KS into buffer WBUF (wave-private 64 cols, 4 x gl16, packed source)
#define WSTAGE(WBUF, KS) do{ _Pragma("unroll") for (int i_ = 0; i_ < 4; ++i_)             \
  gl16((const char*)w1b + (((long)(KS)) << 15) + wso[i_], lds + (WBUF) + wdb[i_]); }while(0)

// issue 6 gather register loads into static slot S (parity PAR fixed per slot)
#define GISS(S, PAR, FV) do{ const float* xf_ = xb + ((long)(FV) << 16);                  \
  _Pragma("unroll") for (int o_ = 0; o_ < 3; ++o_)                                        \
  _Pragma("unroll") for (int e_ = 0; e_ < 2; ++e_)                                        \
    g##S[o_][e_] = xf_[poff[PAR][o_][e_]]; }while(0)

// cvt slot -> ds_write A-tile into buffer BUF (compiler inserts counted vmcnt for g regs)
#define CVTWR(S, BUF) do{ _Pragma("unroll") for (int o_ = 0; o_ < 3; ++o_){               \
  unsigned pv_ = (unsigned)f2bf(g##S[o_][0]) | ((unsigned)f2bf(g##S[o_][1]) << 16);       \
  *(unsigned*)(lds + (BUF) + awr + (o_ << 9)) = pv_; } }while(0)

// 6 A-frag + 4 W-frag ds_read_b128, 24 MFMA
#define MM(ABUF, WBUF) do{ bf16x8 af_[6], bw_[4];                                         \
  _Pragma("unroll") for (int fm_ = 0; fm_ < 6; ++fm_)                                     \
    af_[fm_] = *(const bf16x8*)(lds + (ABUF) + ard + fm_*256);                            \
  _Pragma("unroll") for (int cn_ = 0; cn_ < 4; ++cn_)                                     \
    bw_[cn_] = *(const bf16x8*)(lds + (WBUF) + wrd[cn_]);                                 \
  _Pragma("unroll") for (int cn_ = 0; cn_ < 4; ++cn_)                                     \
  _Pragma("unroll") for (int fm_ = 0; fm_ < 6; ++fm_)                                     \
    acc[fm_][cn_] = __builtin_amdgcn_mfma_f32_16x16x32_bf16(af_[fm_], bw_[cn_], acc[fm_][cn_], 0, 0, 0); \
}while(0)

// full drain + barrier (R4's proven sync; all flights are >= 1 superstep so cost ~0)
#define DBAR() do{ asm volatile("s_waitcnt vmcnt(0) lgkmcnt(0)" ::: "memory");            \
  __builtin_amdgcn_s_barrier(); asm volatile("" ::: "memory"); }while(0)

#define A2SUB(ss, cc) do{                                                                 \
  bf16x8 a2[6];                                                                           \
  _Pragma("unroll") for (int fm = 0; fm < 6; ++fm){                                       \
    int byt = (((fm << 4) + lr) << 10) + ((ss) << 6) + (q << 4);                          \
    byt ^= (lr & 7) << 4;                                                                 \
    a2[fm] = *(const bf16x8*)(lds + byt);                                                 \
  }                                                                                       \
  _Pragma("unroll") for (int cn = 0; cn < 4; ++cn)                                        \
    _Pragma("unroll") for (int fm = 0; fm < 6; ++fm)                                      \
      acc2[fm][cn] = __builtin_amdgcn_mfma_f32_16x16x32_bf16(a2[fm], cc[cn], acc2[fm][cn], 0, 0, 0); \
}while(0)

// Block = (b, 32-t tile): 256 blocks, 512 threads (8 waves). Each wave: [96m x 64n].
__global__ __launch_bounds__(512, 2)
void fused_kernel(const float* __restrict__ x,
                  const float* __restrict__ b1v,
                  const float* __restrict__ b2v,
                  const unsigned short* __restrict__ w1b,
                  const unsigned short* __restrict__ w2b,
                  float* __restrict__ out)
{
  __shared__ char lds[155648];
  const int bid = blockIdx.x;
  const int b   = bid >> 3;
  const int t0  = (bid & 7) << 5;

  const int tid  = threadIdx.x;
  const int w    = tid >> 6;
  const int lane = tid & 63;
  const int q    = lane >> 4;
  const int lr   = lane & 15;
  const int u    = tid >> 5;          // [0,16): k-pair index for gather
  const int tt   = tid & 31;          // t within tile for gather

  // gather source offsets: k = par*32 + 2u + e
  int poff[2][3][2];
#pragma unroll
  for (int par = 0; par < 2; ++par)
#pragma unroll
    for (int e = 0; e < 2; ++e){
      const int k = par * 32 + 2 * u + e;
      const int r = dR[k], c = dC[k];
#pragma unroll
      for (int o = 0; o < 3; ++o){
        const int v = o - 1;                         // mean over o is order-free
        poff[par][o][e] = ((((r - v) & 15) << 4) | ((c - v) & 15)) << 8;
      }
    }
  const float* xb = x + (((long)b << 21) + t0 + tt);

  // A-tile: [kb4][row96][16B], kb stride 1536; row = o*32 + tt
  const int awr = ((u >> 2) * 1536) + (tt << 4) + ((u & 3) << 2);   // + o*512
  const int ard = q * 1536 + (lr << 4);                              // + fm*256
  // W-frag read: [col][4 slot][16B], slot = q ^ ((col>>1)&3)
  int wrd[4];
#pragma unroll
  for (int cn = 0; cn < 4; ++cn){
    const int col = (w << 6) + (cn << 4) + lr;
    wrd[cn] = col * 64 + ((q ^ ((col >> 1) & 3)) << 4);
  }
  // W stage: linear LDS dest (wave-uniform), inverse-swizzled packed global source
  int wso[4], wdb[4];
#pragma unroll
  for (int i = 0; i < 4; ++i){
    const int colb = (w << 6) + (i << 4);
    const int col  = colb + (lane >> 2);
    wso[i] = col * 64 + (((lane & 3) ^ ((col >> 1) & 3)) << 4);
    wdb[i] = colb * 64;
  }
  float b1c[4];
#pragma unroll
  for (int cn = 0; cn < 4; ++cn) b1c[cn] = b1v[(w << 6) + (cn << 4) + lr];

  f32x4 acc[6][4];
#pragma unroll
  for (int fm = 0; fm < 6; ++fm)
#pragma unroll
    for (int cn = 0; cn < 4; ++cn)
      acc[fm][cn] = f32x4{0.f, 0.f, 0.f, 0.f};

  float g0[3][2], g1[3][2], g2[3][2], g3[3][2];

  // ---------------- prologue: tiles 0..3 in flight, W 0,1 staged ----------------
  {
    GISS(0, 0, 0);                   // tile 0 (f=0, par=0)
    GISS(1, 1, 0);                   // tile 1 (f=0, par=1)
    WSTAGE(LW0, 0);
    WSTAGE(LW1, 1);
    GISS(2, 0, 1);                   // tile 2 (f=1, par=0)
    GISS(3, 1, 1);                   // tile 3 (f=1, par=1)
    CVTWR(0, LA_0);                  // auto-waits g0 (counted)
    CVTWR(1, LA_1);                  // auto-waits g1
    DBAR();                          // drains W0,W1 + g2,g3 (prologue-only cost)
  }

  // ---------------- phase 1: 32 supersteps (2 K-steps each), ONE drain+barrier per
  // superstep S: stage W(2S+2, 2S+3); issue gathers (2S+4, 2S+5); MM(2S),(2S+1);
  //              cvt tiles (2S+2),(2S+3); drain; barrier.
#pragma unroll 1
  for (int it = 0; it < 15; ++it){
    const int N0 = it << 2;
    // S even (steps N0, N0+1; bufs 0,1)
    WSTAGE(LW2, N0 + 2); WSTAGE(LW3, N0 + 3);
    GISS(0, 0, (N0 + 4) >> 1); GISS(1, 1, (N0 + 4) >> 1);   // tiles N0+4, N0+5
    MM(LA_0, LW0); MM(LA_1, LW1);
    CVTWR(2, LA_2); CVTWR(3, LA_3);                          // tiles N0+2, N0+3
    DBAR();
    // S odd (steps N0+2, N0+3; bufs 2,3)
    WSTAGE(LW0, N0 + 4); WSTAGE(LW1, N0 + 5);
    GISS(2, 0, (N0 + 6) >> 1); GISS(3, 1, (N0 + 6) >> 1);   // tiles N0+6, N0+7
    MM(LA_2, LW2); MM(LA_3, LW3);
    CVTWR(0, LA_0); CVTWR(1, LA_1);                          // tiles N0+4, N0+5
    DBAR();
  }
  // tail S=30 (steps 60,61): stage W62,63; cvt tiles 62,63 (g2,g3); no new gathers
  WSTAGE(LW2, 62); WSTAGE(LW3, 63);
  MM(LA_0, LW0); MM(LA_1, LW1);
  CVTWR(2, LA_2); CVTWR(3, LA_3);
  DBAR();
  // tail S=31 (steps 62,63)
  MM(LA_2, LW2); MM(LA_3, LW3);
  DBAR();

  // ---------------- epilogue 1: bias + leaky -> A1 bf16 (XOR-swizzled) --------
#pragma unroll
  for (int cn = 0; cn < 4; ++cn){
    const int h  = (w << 6) + (cn << 4) + lr;
#pragma unroll
    for (int fm = 0; fm < 6; ++fm)
#pragma unroll
      for (int r = 0; r < 4; ++r){
        float vv = acc[fm][cn][r] + b1c[cn];
        vv = vv > 0.f ? vv : 0.01f * vv;
        const int row = (fm << 4) + (q << 2) + r;    // D row = 4*(lane>>4)+reg
        int byt = (row << 10) + (h << 1);
        byt ^= (row & 7) << 4;
        *(unsigned short*)(lds + byt) = f2bf(vv);
      }
  }
  DBAR();

  // ---------------- phase 2: K=512 vs packed W2 (L2 reg frags), barrier-free ----
  int w2off[4];
  float b2c[4];
#pragma unroll
  for (int cn = 0; cn < 4; ++cn){
    const int col = (w << 6) + (cn << 4) + lr;
    w2off[cn] = col * 64 + (q << 4);
    b2c[cn] = b2v[col];
  }
  const char* w2c = (const char*)w2b;
  f32x4 acc2[6][4];
#pragma unroll
  for (int fm = 0; fm < 6; ++fm)
#pragma unroll
    for (int cn = 0; cn < 4; ++cn)
      acc2[fm][cn] = f32x4{0.f, 0.f, 0.f, 0.f};

  bf16x8 c0[4], c1[4];
#pragma unroll
  for (int cn = 0; cn < 4; ++cn) c0[cn] = *(const bf16x8*)(w2c + w2off[cn]);

#pragma unroll 1
  for (int it2 = 0; it2 < 8; ++it2){
    const int s0 = it2 << 1;
#pragma unroll
    for (int cn = 0; cn < 4; ++cn)
      c1[cn] = *(const bf16x8*)(w2c + (((long)(s0 + 1)) << 15) + w2off[cn]);
    A2SUB(s0, c0);
    if (it2 < 7){
#pragma unroll
      for (int cn = 0; cn < 4; ++cn)
        c0[cn] = *(const bf16x8*)(w2c + (((long)(s0 + 2)) << 15) + w2off[cn]);
    }
    A2SUB(s0 + 1, c1);
  }

  // ---------------- epilogue 2: bias + leaky + mean(o) -> [B,H,T] -------------
#pragma unroll
  for (int cn = 0; cn < 4; ++cn){
    const int h  = (w << 6) + (cn << 4) + lr;
#pragma unroll
    for (int p = 0; p < 2; ++p){
      f32x4 ov;
#pragma unroll
      for (int r = 0; r < 4; ++r){
        float s = 0.f;
#pragma unroll
        for (int oo = 0; oo < 3; ++oo){
          float vv = acc2[oo * 2 + p][cn][r] + b2c[cn];
          vv = vv > 0.f ? vv : 0.01f * vv;
          s += vv;
        }
        ov[r] = s * (1.f / 3.f);
      }
      *(f32x4*)(out + (((long)b * 512 + h) << 8) + t0 + (p << 4) + (q << 2)) = ov;
    }
  }
}

extern "C" void kernel_launch(void* const* d_in, const int* in_sizes, int n_in,
                              void* d_out, int out_size, void* d_ws, size_t ws_size,
                              hipStream_t stream){
  const float* x  = (const float*)d_in[0];
  const float* w1 = (const float*)d_in[1];
  const float* b1 = (const float*)d_in[2];
  const float* w2 = (const float*)d_in[3];
  const float* b2 = (const float*)d_in[4];
  unsigned short* w1b = (unsigned short*)d_ws;            // packed W1: 2 MiB
  unsigned short* w2b = w1b + 512 * 2048;                 // packed W2: 0.5 MiB
  conv_w_kernel<<<1280, 256, 0, stream>>>(w1, w2, w1b, w2b);
  fused_kernel<<<256, 512, 0, stream>>>(x, b1, b2, w1b, w2b, (float*)d_out);
}

// Round 12
// 79.853 us; speedup vs baseline: 3.0760x; 1.2390x over previous
//
#include <hip/hip_runtime.h>
#include <stdint.h>

typedef __attribute__((ext_vector_type(8))) __bf16 bf16x8;
typedef __attribute__((ext_vector_type(4))) float f32x4;

// Selected upper-tri circular-adjacency pairs (r,c), row-major triu order. K=64.
__device__ const unsigned char dR[64] = {
  0,0,0,0,0,0,0,
  1,1,1,1,1,1,
  2,2,2,2,2,
  3,3,3,3,
  4,4,4,4,
  5,5,5,5,
  6,6,6,6,
  7,7,7,7,
  8,8,8,8,
  9,9,9,9,
  10,10,10,10,
  11,11,11,11,
  12,12,12,12,
  13,13,13,
  14,14,
  15};
__device__ const unsigned char dC[64] = {
  0,1,2,3,13,14,15,
  1,2,3,4,14,15,
  2,3,4,5,15,
  3,4,5,6,
  4,5,6,7,
  5,6,7,8,
  6,7,8,9,
  7,8,9,10,
  8,9,10,11,
  9,10,11,12,
  10,11,12,13,
  11,12,13,14,
  12,13,14,15,
  13,14,15,
  14,15,
  15};

__device__ __forceinline__ unsigned short f2bf(float x){
  unsigned u = __builtin_bit_cast(unsigned, x);
  return (unsigned short)((u + 0x7FFFu + ((u >> 16) & 1u)) >> 16);
}

__device__ __forceinline__ void gl16(const void* g, void* l){
  __builtin_amdgcn_global_load_lds((const __attribute__((address_space(1))) unsigned int*)g,
                                   (__attribute__((address_space(3))) unsigned int*)l,
                                   16, 0, 0);
}

// fp32 -> bf16 conversion + K-STEP PACKING: W1 -> [64 ks][512 col][32 k] bf16,
// W2 -> [16 ks][512 col][32 k] bf16. Contiguous 1KB per (ks, 16-col chunk).
__global__ void conv_w_kernel(const float* __restrict__ w1, const float* __restrict__ w2,
                              unsigned short* __restrict__ o1, unsigned short* __restrict__ o2){
  int i = blockIdx.x * 256 + threadIdx.x;
  if (i < 262144){                                  // W1: [512][2048] fp32, float4 idx
    float4 v = ((const float4*)w1)[i];
    ushort4 pk; pk.x=f2bf(v.x); pk.y=f2bf(v.y); pk.z=f2bf(v.z); pk.w=f2bf(v.w);
    const int col = i >> 9;
    const int kb  = (i & 511) << 2;
    const int ks  = kb >> 5, ko = kb & 31;
    ((ushort4*)o1)[(ks << 12) + (col << 3) + (ko >> 2)] = pk;
  } else {
    int j = i - 262144;
    if (j < 65536){                                 // W2: [512][512] fp32
      float4 v = ((const float4*)w2)[j];
      ushort4 pk; pk.x=f2bf(v.x); pk.y=f2bf(v.y); pk.z=f2bf(v.z); pk.w=f2bf(v.w);
      const int col = j >> 7;
      const int kb  = (j & 127) << 2;
      const int ks  = kb >> 5, ko = kb & 31;
      ((ushort4*)o2)[(ks << 12) + (col << 3) + (ko >> 2)] = pk;
    }
  }
}

// LDS: phase 1: W dbuf 2x32KB @ 0/32768 ([512 col][4 slot][16B], slot-swizzled),
//               gather A dbuf 2x6144 @ 65536/71680 ([kb4][96 row][16B]).
//      phase 2: A1 [96 row][512 h] bf16 XOR-swizzled @ [0, 98304) (aliases, post-barrier)
#define LW0 0
#define LW1 32768
#define LA0 65536
#define LA1 71680

// stage W k-step KS into buffer WBUF (wave-private 64 cols, 4 x gl16, packed source)
#define WSTAGE(WBUF, KS) do{ _Pragma("unroll") for (int i_ = 0; i_ < 4; ++i_)             \
  gl16((const char*)w1b + (((long)(KS)) << 15) + wso[i_], lds + (WBUF) + wdb[i_]); }while(0)

// issue 6 gather register loads into static slot S (parity PAR fixed per slot)
#define GISS(S, PAR, FV) do{ const float* xf_ = xb + ((long)(FV) << 16);                  \
  _Pragma("unroll") for (int o_ = 0; o_ < 3; ++o_)                                        \
  _Pragma("unroll") for (int e_ = 0; e_ < 2; ++e_)                                        \
    g##S[o_][e_] = xf_[poff[PAR][o_][e_]]; }while(0)

// cvt slot -> ds_write A-tile into buffer BUF (compiler inserts counted vmcnt for g regs)
#define CVTWR(S, BUF) do{ _Pragma("unroll") for (int o_ = 0; o_ < 3; ++o_){               \
  unsigned pv_ = (unsigned)f2bf(g##S[o_][0]) | ((unsigned)f2bf(g##S[o_][1]) << 16);       \
  *(unsigned*)(lds + (BUF) + awr + (o_ << 9)) = pv_; } }while(0)

// phase-split K-step (m201 template): issue ds_reads + stages + gathers, barrier,
// lgkm(0) + sched fence (rule #18), prio-wrapped MFMA cluster, cvt-write, counted
// vmcnt + lgkm(0), barrier.
#define PSTEP(ABUF, WRBUF, WWBUF, KSN, GS, GP, GF, CS, CBUF, DO_G, DO_W, DO_C, VN) do{    \
  bf16x8 af_[6], bw_[4];                                                                  \
  _Pragma("unroll") for (int fm_ = 0; fm_ < 6; ++fm_)                                     \
    af_[fm_] = *(const bf16x8*)(lds + (ABUF) + ard + fm_*256);                            \
  _Pragma("unroll") for (int cn_ = 0; cn_ < 4; ++cn_)                                     \
    bw_[cn_] = *(const bf16x8*)(lds + (WRBUF) + wrd[cn_]);                                \
  if (DO_W) WSTAGE(WWBUF, KSN);                                                           \
  if (DO_G) GISS(GS, GP, GF);                                                             \
  __builtin_amdgcn_s_barrier();                                                           \
  asm volatile("s_waitcnt lgkmcnt(0)" ::: "memory");                                      \
  __builtin_amdgcn_sched_barrier(0);                                                      \
  __builtin_amdgcn_s_setprio(1);                                                          \
  _Pragma("unroll") for (int cn_ = 0; cn_ < 4; ++cn_)                                     \
  _Pragma("unroll") for (int fm_ = 0; fm_ < 6; ++fm_)                                     \
    acc[fm_][cn_] = __builtin_amdgcn_mfma_f32_16x16x32_bf16(af_[fm_], bw_[cn_], acc[fm_][cn_], 0, 0, 0); \
  __builtin_amdgcn_s_setprio(0);                                                          \
  if (DO_C) CVTWR(CS, CBUF);                                                              \
  asm volatile("s_waitcnt vmcnt(" #VN ") lgkmcnt(0)" ::: "memory");                       \
  __builtin_amdgcn_s_barrier();                                                           \
  asm volatile("" ::: "memory");                                                          \
}while(0)

#define A2SUB(ss, cc) do{                                                                 \
  bf16x8 a2[6];                                                                           \
  _Pragma("unroll") for (int fm = 0; fm < 6; ++fm){                                       \
    int byt = (((fm << 4) + lr) << 10) + ((ss) << 6) + (q << 4);                          \
    byt ^= (lr & 7) << 4;                                                                 \
    a2[fm] = *(const bf16x8*)(lds + byt);                                                 \
  }                                                                                       \
  _Pragma("unroll") for (int cn = 0; cn < 4; ++cn)                                        \
    _Pragma("unroll") for (int fm = 0; fm < 6; ++fm)                                      \
      acc2[fm][cn] = __builtin_amdgcn_mfma_f32_16x16x32_bf16(a2[fm], cc[cn], acc2[fm][cn], 0, 0, 0); \
}while(0)

// Block = (b, 32-t tile): 256 blocks, 512 threads (8 waves). Each wave: [96m x 64n].
__global__ __launch_bounds__(512, 2)
void fused_kernel(const float* __restrict__ x,
                  const float* __restrict__ b1v,
                  const float* __restrict__ b2v,
                  const unsigned short* __restrict__ w1b,
                  const unsigned short* __restrict__ w2b,
                  float* __restrict__ out)
{
  __shared__ char lds[98304];
  const int bid = blockIdx.x;
  const int b   = bid >> 3;
  const int t0  = (bid & 7) << 5;

  const int tid  = threadIdx.x;
  const int w    = tid >> 6;
  const int lane = tid & 63;
  const int q    = lane >> 4;
  const int lr   = lane & 15;
  const int u    = tid >> 5;          // [0,16): k-pair index for gather
  const int tt   = tid & 31;          // t within tile for gather

  // gather source offsets: k = par*32 + 2u + e
  int poff[2][3][2];
#pragma unroll
  for (int par = 0; par < 2; ++par)
#pragma unroll
    for (int e = 0; e < 2; ++e){
      const int k = par * 32 + 2 * u + e;
      const int r = dR[k], c = dC[k];
#pragma unroll
      for (int o = 0; o < 3; ++o){
        const int v = o - 1;                         // mean over o is order-free
        poff[par][o][e] = ((((r - v) & 15) << 4) | ((c - v) & 15)) << 8;
      }
    }
  const float* xb = x + (((long)b << 21) + t0 + tt);

  // A-tile: [kb4][row96][16B], kb stride 1536
  const int awr = ((u >> 2) * 1536) + (tt << 4) + ((u & 3) << 2);   // + o*512
  const int ard = q * 1536 + (lr << 4);                              // + fm*256
  // W-frag read: [col][4 slot][16B], slot = q ^ ((col>>1)&3)
  int wrd[4];
#pragma unroll
  for (int cn = 0; cn < 4; ++cn){
    const int col = (w << 6) + (cn << 4) + lr;
    wrd[cn] = col * 64 + ((q ^ ((col >> 1) & 3)) << 4);
  }
  // W stage: linear LDS dest (wave-uniform), inverse-swizzled packed global source
  int wso[4], wdb[4];
#pragma unroll
  for (int i = 0; i < 4; ++i){
    const int colb = (w << 6) + (i << 4);
    const int col  = colb + (lane >> 2);
    wso[i] = col * 64 + (((lane & 3) ^ ((col >> 1) & 3)) << 4);
    wdb[i] = colb * 64;
  }
  float b1c[4];
#pragma unroll
  for (int cn = 0; cn < 4; ++cn) b1c[cn] = b1v[(w << 6) + (cn << 4) + lr];

  f32x4 acc[6][4];
#pragma unroll
  for (int fm = 0; fm < 6; ++fm)
#pragma unroll
    for (int cn = 0; cn < 4; ++cn)
      acc[fm][cn] = f32x4{0.f, 0.f, 0.f, 0.f};

  float g0[3][2], g1[3][2];

  // ---------------- prologue ----------------
  // tile0 -> LA0 directly; W0 -> LW0; g1 <- tile1 in flight; counted drain.
  {
    float gp[3][2];
#pragma unroll
    for (int o_ = 0; o_ < 3; ++o_)
#pragma unroll
      for (int e_ = 0; e_ < 2; ++e_)
        gp[o_][e_] = xb[poff[0][o_][e_]];          // tile 0 (f=0, par=0)
    WSTAGE(LW0, 0);                                // W k-step 0
    GISS(1, 1, 0);                                 // tile 1 (f=0, par=1)
#pragma unroll
    for (int o_ = 0; o_ < 3; ++o_){
      unsigned pv_ = (unsigned)f2bf(gp[o_][0]) | ((unsigned)f2bf(gp[o_][1]) << 16);
      *(unsigned*)(lds + LA0 + awr + (o_ << 9)) = pv_;
    }
    asm volatile("s_waitcnt vmcnt(6) lgkmcnt(0)" ::: "memory");   // W0 done, g1 in flight
    __builtin_amdgcn_s_barrier();
    asm volatile("" ::: "memory");
  }

  // ---------------- phase 1: 64 K-steps, double-barrier phase schedule ----------
  // step N: ds_read (LA,LW)[N%2]; stage W(N+1)->LW[(N+1)%2]; issue gather tile N+2
  //         (slot N%2); MFMA; cvt tile N+1 (slot (N+1)%2) -> LA[(N+1)%2].
#pragma unroll 1
  for (int it = 0; it < 31; ++it){
    PSTEP(LA0, LW0, LW1, (it << 1) + 1, 0, 0, it + 1, 1, LA1, 1, 1, 1, 6);  // even step 2it
    PSTEP(LA1, LW1, LW0, (it << 1) + 2, 1, 1, it + 1, 0, LA0, 1, 1, 1, 6);  // odd step 2it+1
  }
  PSTEP(LA0, LW0, LW1, 63, 0, 0, 0, 1, LA1, 0, 1, 1, 0);   // step 62: stage W63, cvt tile63
  PSTEP(LA1, LW1, LW0,  0, 0, 0, 0, 0, LA0, 0, 0, 0, 0);   // step 63: compute only

  // ---------------- epilogue 1: bias + leaky -> A1 bf16 (XOR-swizzled) --------
#pragma unroll
  for (int cn = 0; cn < 4; ++cn){
    const int h  = (w << 6) + (cn << 4) + lr;
#pragma unroll
    for (int fm = 0; fm < 6; ++fm)
#pragma unroll
      for (int r = 0; r < 4; ++r){
        float vv = acc[fm][cn][r] + b1c[cn];
        vv = vv > 0.f ? vv : 0.01f * vv;
        const int row = (fm << 4) + (q << 2) + r;    // D row = 4*(lane>>4)+reg
        int byt = (row << 10) + (h << 1);
        byt ^= (row & 7) << 4;
        *(unsigned short*)(lds + byt) = f2bf(vv);
      }
  }
  asm volatile("s_waitcnt lgkmcnt(0)" ::: "memory");
  __builtin_amdgcn_s_barrier();
  asm volatile("" ::: "memory");

  // ---------------- phase 2: K=512 vs packed W2 (L2 reg frags), barrier-free ----
  int w2off[4];
  float b2c[4];
#pragma unroll
  for (int cn = 0; cn < 4; ++cn){
    const int col = (w << 6) + (cn << 4) + lr;
    w2off[cn] = col * 64 + (q << 4);
    b2c[cn] = b2v[col];
  }
  const char* w2c = (const char*)w2b;
  f32x4 acc2[6][4];
#pragma unroll
  for (int fm = 0; fm < 6; ++fm)
#pragma unroll
    for (int cn = 0; cn < 4; ++cn)
      acc2[fm][cn] = f32x4{0.f, 0.f, 0.f, 0.f};

  bf16x8 c0[4], c1[4];
#pragma unroll
  for (int cn = 0; cn < 4; ++cn) c0[cn] = *(const bf16x8*)(w2c + w2off[cn]);

#pragma unroll 1
  for (int it2 = 0; it2 < 8; ++it2){
    const int s0 = it2 << 1;
#pragma unroll
    for (int cn = 0; cn < 4; ++cn)
      c1[cn] = *(const bf16x8*)(w2c + (((long)(s0 + 1)) << 15) + w2off[cn]);
    A2SUB(s0, c0);
    if (it2 < 7){
#pragma unroll
      for (int cn = 0; cn < 4; ++cn)
        c0[cn] = *(const bf16x8*)(w2c + (((long)(s0 + 2)) << 15) + w2off[cn]);
    }
    A2SUB(s0 + 1, c1);
  }

  // ---------------- epilogue 2: bias + leaky + mean(o) -> [B,H,T] -------------
#pragma unroll
  for (int cn = 0; cn < 4; ++cn){
    const int h  = (w << 6) + (cn << 4) + lr;
#pragma unroll
    for (int p = 0; p < 2; ++p){
      f32x4 ov;
#pragma unroll
      for (int r = 0; r < 4; ++r){
        float s = 0.f;
#pragma unroll
        for (int oo = 0; oo < 3; ++oo){
          float vv = acc2[oo * 2 + p][cn][r] + b2c[cn];
          vv = vv > 0.f ? vv : 0.01f * vv;
          s += vv;
        }
        ov[r] = s * (1.f / 3.f);
      }
      *(f32x4*)(out + (((long)b * 512 + h) << 8) + t0 + (p << 4) + (q << 2)) = ov;
    }
  }
}

extern "C" void kernel_launch(void* const* d_in, const int* in_sizes, int n_in,
                              void* d_out, int out_size, void* d_ws, size_t ws_size,
                              hipStream_t stream){
  const float* x  = (const float*)d_in[0];
  const float* w1 = (const float*)d_in[1];
  const float* b1 = (const float*)d_in[2];
  const float* w2 = (const float*)d_in[3];
  const float* b2 = (const float*)d_in[4];
  unsigned short* w1b = (unsigned short*)d_ws;            // packed W1: 2 MiB
  unsigned short* w2b = w1b + 512 * 2048;                 // packed W2: 0.5 MiB
  conv_w_kernel<<<1280, 256, 0, stream>>>(w1, w2, w1b, w2b);
  fused_kernel<<<256, 512, 0, stream>>>(x, b1, b2, w1b, w2b, (float*)d_out);
}